// Round 5
// baseline (204.942 us; speedup 1.0000x reference)
//
#include <hip/hip_runtime.h>

// MinVarianceWeightsLayer: for each of B SPD 64x64 fp32 matrices S,
// solve S z = 1, output w = z / sum(z) as [B, 64, 1] fp32.
//
// One wave per matrix, lane i owns row i in VGPRs as 32 float2 pairs.
// Gaussian elimination without pivoting (SPD, kappa~41 -> stable).
//
// ROUND-4 EVIDENCE: OccupancyPercent ~25% (= 2 waves/SIMD) despite
// VGPR_Count=68 and a grid offering 32 waves/CU. Conclusion: VGPR_Count is
// ARCH regs only -- the compiler pushed row[] into AGPRs (unified file!) to
// satisfy its arch-VGPR occupancy heuristic, costing accvgpr_read/write
// around every FMA (explains the 2x instr gap AND the low real occupancy).
// ROUND-5 FIX: amdgpu_waves_per_eu(2,4) clamps the occupancy TARGET from
// above -> 128-arch-VGPR budget -> row[] stays in arch VGPRs, 4 waves/SIMD.

#define NN 64

typedef float v2f __attribute__((ext_vector_type(2)));

template <int I> struct ic { static constexpr int value = I; };

template <int Start, int End, typename F>
__device__ __forceinline__ void static_for(F&& f) {
    if constexpr (Start < End) {
        f(ic<Start>{});
        static_for<Start + 1, End>(static_cast<F&&>(f));
    }
}

__device__ __forceinline__ float rlane(float v, int lane) {
    return __int_as_float(__builtin_amdgcn_readlane(__float_as_int(v), lane));
}

__device__ __forceinline__ float frcp(float x) {
#if __has_builtin(__builtin_amdgcn_rcpf)
    return __builtin_amdgcn_rcpf(x);   // ~1 ulp; plenty vs 2e-3 abs threshold
#else
    return 1.0f / x;
#endif
}

__device__ __forceinline__ v2f fma2(v2f a, v2f b, v2f c) {
#if __has_builtin(__builtin_elementwise_fma)
    return __builtin_elementwise_fma(a, b, c);   // -> v_pk_fma_f32
#else
    v2f r; r.x = fmaf(a.x, b.x, c.x); r.y = fmaf(a.y, b.y, c.y); return r;
#endif
}

__global__ __launch_bounds__(256)
__attribute__((amdgpu_waves_per_eu(2, 4)))
void minvar_kernel(const float* __restrict__ sigma,
                   float* __restrict__ out,
                   int batch) {
    const int lane = threadIdx.x & 63;
    const int wid  = threadIdx.x >> 6;     // 4 waves per block, 1 matrix each
    const int bid  = blockIdx.x * 4 + wid;
    if (bid >= batch) return;

    const float* __restrict__ p = sigma + (size_t)bid * (NN * NN) + (size_t)lane * NN;

    // Own row as 32 float2 pairs (all indices compile-time -> SROA to VGPRs).
    v2f r[NN / 2];
    static_for<0, NN / 4>([&](auto j4c) {
        constexpr int j4 = decltype(j4c)::value;
        float4 v = reinterpret_cast<const float4*>(p)[j4];
        r[2 * j4 + 0] = v2f{v.x, v.y};
        r[2 * j4 + 1] = v2f{v.z, v.w};
    });

    float b = 1.0f;   // RHS: ones

    // ---- Forward elimination: row_i -= (S[i][k]/S[k][k]) * row_k, i > k ----
    static_for<0, NN>([&](auto kc) {
        constexpr int k  = decltype(kc)::value;
        constexpr int pk = k / 2;
        const float ekk  = (k & 1) ? r[pk].y : r[pk].x;   // lane's element k
        const float pivot = rlane(ekk, k);                // S[k][k] (uniform)
        const float invp  = frcp(pivot);
        const float nf    = (lane > k) ? (-ekk * invp) : 0.0f;
        const v2f   nf2   = v2f{nf, nf};
        b = fmaf(nf, rlane(b, k), b);

        // odd leading element (k even: j=k+1 is .y of pair pk)
        if constexpr ((k & 1) == 0) {
            const float bcy = rlane(r[pk].y, k);
            r[pk].y = fmaf(nf, bcy, r[pk].y);
        }

        // full pairs, batched 4-at-a-time: readlanes first, then pk_fmas
        constexpr int P0 = pk + 1;
        static_for<0, (NN / 2 - P0 + 3) / 4>([&](auto gc) {
            constexpr int g0 = P0 + 4 * decltype(gc)::value;
            v2f bc[4];
            static_for<0, 4>([&](auto tc) {
                constexpr int t = decltype(tc)::value;
                if constexpr (g0 + t < NN / 2)
                    bc[t] = v2f{rlane(r[g0 + t].x, k), rlane(r[g0 + t].y, k)};
            });
            static_for<0, 4>([&](auto tc) {
                constexpr int t = decltype(tc)::value;
                if constexpr (g0 + t < NN / 2)
                    r[g0 + t] = fma2(nf2, bc[t], r[g0 + t]);
            });
        });
    });

    // ---- Back substitution: U z = y (U[i][j] = r[...][j] on lane i) ----
    static_for<0, NN>([&](auto kk) {
        constexpr int k  = NN - 1 - decltype(kk)::value;
        constexpr int pk = k / 2;
        const float ekk  = (k & 1) ? r[pk].y : r[pk].x;
        const float ukk  = rlane(ekk, k);
        const float yk   = rlane(b, k);
        const float zk   = yk * frcp(ukk);
        const float upd  = (lane < k) ? (-ekk) : 0.0f;
        b = (lane == k) ? zk : fmaf(upd, zk, b);
    });

    // ---- Normalize: w = z / sum(z) ----
    float total = b;
    #pragma unroll
    for (int off = 32; off >= 1; off >>= 1)
        total += __shfl_xor(total, off, 64);

    out[(size_t)bid * NN + lane] = b * frcp(total);
}

extern "C" void kernel_launch(void* const* d_in, const int* in_sizes, int n_in,
                              void* d_out, int out_size, void* d_ws, size_t ws_size,
                              hipStream_t stream) {
    const float* sigma = (const float*)d_in[0];
    float* out = (float*)d_out;
    const int batch = in_sizes[0] / (NN * NN);      // 8192
    const int blocks = (batch + 3) / 4;             // 4 matrices per 256-thr block
    minvar_kernel<<<blocks, 256, 0, stream>>>(sigma, out, batch);
}